// Round 1
// baseline (476.496 us; speedup 1.0000x reference)
//
#include <hip/hip_runtime.h>

// Differential attention, fused flash-style, bf16 MFMA (gfx950).
// B=4, T=1024, 16 head-pairs (32 QK heads), D_HEAD=64, V dim=128, causal.

typedef short bf16x8 __attribute__((ext_vector_type(8)));
typedef float f32x4  __attribute__((ext_vector_type(4)));

constexpr int   TSEQ        = 1024;
constexpr int   DQK         = 64;
constexpr int   DVDIM       = 128;
constexpr float SCALING     = 0.125f;                 // 1/sqrt(64)
constexpr float LAMBDA_INIT = 0.7836057665316245f;    // 0.8 - 0.6*exp(-3.6)
constexpr float ONE_MINUS_LI= 1.0f - LAMBDA_INIT;
constexpr float RMS_EPS     = 1e-6f;
constexpr float LOG2E       = 1.4426950408889634f;

// round-to-nearest-even fp32 -> bf16 bits
__device__ __forceinline__ unsigned short f2bf(float f) {
    union { float f; unsigned u; } v; v.f = f;
    unsigned r = v.u + 0x7fffu + ((v.u >> 16) & 1u);
    return (unsigned short)(r >> 16);
}

__global__ __launch_bounds__(256, 2)
void diff_attn_kernel(const float* __restrict__ qg, const float* __restrict__ kg,
                      const float* __restrict__ vg,
                      const float* __restrict__ lq1, const float* __restrict__ lk1,
                      const float* __restrict__ lq2, const float* __restrict__ lk2,
                      const float* __restrict__ rmsw, float* __restrict__ out)
{
    // K tiles for the 2 heads of the pair: rows padded 64->72 shorts (144B, 16B-aligned)
    __shared__ ushort Klds[2][32][72];
    // V tile transposed [dv][s]: rows padded 32->36 shorts (72B, 8B-aligned)
    __shared__ ushort Vt[128][36];
    // per-wave P scratch (C-layout -> A-layout round trip), rows padded 32->40 (80B)
    __shared__ ushort Plds[4][2][16][40];

    const int qt   = gridDim.x - 1 - blockIdx.x;  // heavy q-tiles first
    const int hp   = blockIdx.y;
    const int b    = blockIdx.z;
    const int t    = threadIdx.x;
    const int w    = t >> 6;
    const int lane = t & 63;
    const int n    = lane & 15;   // m/n index of MFMA fragments
    const int quad = lane >> 4;   // k-chunk / row-group index
    const int qbase = qt * 64;
    const int qw0   = qbase + w * 16;  // this wave's first q row

    // ---- lambda_final for this head pair (redundant per-thread; tiny) ----
    float a1 = 0.f, a2 = 0.f;
    for (int i = 0; i < 64; ++i) {
        a1 += lq1[hp*64+i] * lk1[hp*64+i];
        a2 += lq2[hp*64+i] * lk2[hp*64+i];
    }
    const float lambda = __expf(a1) - __expf(a2) + LAMBDA_INIT;

    // ---- Q fragments, held in registers for the whole K loop ----
    // A-frag layout: A[m=lane&15][k=quad*8+j]; two k-steps of 32 cover D=64.
    bf16x8 Qf[2][2];
    #pragma unroll
    for (int h = 0; h < 2; ++h) {
        const float* qp = qg + (((size_t)(b*32 + hp*2 + h)) * TSEQ + (qw0 + n)) * DQK + quad*8;
        #pragma unroll
        for (int ks = 0; ks < 2; ++ks) {
            float4 x = *(const float4*)(qp + ks*32);
            float4 y = *(const float4*)(qp + ks*32 + 4);
            bf16x8 f;
            f[0]=(short)f2bf(x.x); f[1]=(short)f2bf(x.y); f[2]=(short)f2bf(x.z); f[3]=(short)f2bf(x.w);
            f[4]=(short)f2bf(y.x); f[5]=(short)f2bf(y.y); f[6]=(short)f2bf(y.z); f[7]=(short)f2bf(y.w);
            Qf[h][ks] = f;
        }
    }

    // ---- online-softmax state + O accumulators (both heads) ----
    f32x4 O[2][8];
    #pragma unroll
    for (int h = 0; h < 2; ++h)
        #pragma unroll
        for (int d = 0; d < 8; ++d) O[h][d] = (f32x4){0.f,0.f,0.f,0.f};
    float m_[2][4], l_[2][4];
    #pragma unroll
    for (int h = 0; h < 2; ++h)
        #pragma unroll
        for (int r = 0; r < 4; ++r) { m_[h][r] = -__builtin_huge_valf(); l_[h][r] = 0.f; }

    const float* kb = kg + ((size_t)(b*32 + hp*2)) * TSEQ * DQK;
    const float* vb = vg + ((size_t)(b*16 + hp))   * TSEQ * DVDIM;

    const int nT = (qbase + 64) >> 5;   // s-tiles of 32, causal upper bound
    for (int tile = 0; tile < nT; ++tile) {
        const int sbase = tile << 5;
        __syncthreads();   // previous iteration's readers done

        // ---- stage K (2 heads x 32 s x 64 d), coalesced 1KB/wave/instr ----
        #pragma unroll
        for (int i = 0; i < 4; ++i) {
            int f  = i*256 + t;
            int h  = f >> 9, sr = (f >> 4) & 31, d4 = f & 15;
            float4 ld = *(const float4*)(kb + ((size_t)h*TSEQ + sbase + sr)*DQK + d4*4);
            ushort4 st = { f2bf(ld.x), f2bf(ld.y), f2bf(ld.z), f2bf(ld.w) };
            *(ushort4*)&Klds[h][sr][d4*4] = st;
        }
        // ---- stage V transposed: thread owns 2 s-rows x 8 dv, packs s-pairs ----
        {
            const int dvb = (t & 15) * 8;
            const int s0  = (t >> 4) * 2;
            const float* vp = vb + (size_t)(sbase + s0)*DVDIM + dvb;
            float4 r0a = *(const float4*)vp,        r0b = *(const float4*)(vp+4);
            float4 r1a = *(const float4*)(vp+DVDIM), r1b = *(const float4*)(vp+DVDIM+4);
            float v0[8] = {r0a.x,r0a.y,r0a.z,r0a.w,r0b.x,r0b.y,r0b.z,r0b.w};
            float v1[8] = {r1a.x,r1a.y,r1a.z,r1a.w,r1b.x,r1b.y,r1b.z,r1b.w};
            #pragma unroll
            for (int mI = 0; mI < 8; ++mI) {
                unsigned pk = (unsigned)f2bf(v0[mI]) | ((unsigned)f2bf(v1[mI]) << 16);
                *(unsigned*)&Vt[dvb + mI][s0] = pk;
            }
        }
        __syncthreads();

        if (sbase <= qw0 + 15) {   // wave-uniform causal early-out
            float alpha[2][4], P[2][2][4];
            #pragma unroll
            for (int h = 0; h < 2; ++h) {
                // S = Q K^T for two 16-col n-tiles
                f32x4 S[2];
                #pragma unroll
                for (int nt = 0; nt < 2; ++nt) {
                    bf16x8 k0 = *(bf16x8*)&Klds[h][nt*16+n][quad*8];
                    bf16x8 k1 = *(bf16x8*)&Klds[h][nt*16+n][32 + quad*8];
                    f32x4 c = (f32x4){0.f,0.f,0.f,0.f};
                    c = __builtin_amdgcn_mfma_f32_16x16x32_bf16(Qf[h][0], k0, c, 0, 0, 0);
                    c = __builtin_amdgcn_mfma_f32_16x16x32_bf16(Qf[h][1], k1, c, 0, 0, 0);
                    S[nt] = c;
                }
                // scale, causal mask, online softmax (rows = quad*4+r, cols across 16 lanes)
                #pragma unroll
                for (int r = 0; r < 4; ++r) {
                    const int qgl = qw0 + quad*4 + r;
                    float t0 = S[0][r] * SCALING, t1 = S[1][r] * SCALING;
                    if (sbase + n      > qgl) t0 = -__builtin_huge_valf();
                    if (sbase + 16 + n > qgl) t1 = -__builtin_huge_valf();
                    float mx = fmaxf(t0, t1);
                    mx = fmaxf(mx, __shfl_xor(mx, 1));
                    mx = fmaxf(mx, __shfl_xor(mx, 2));
                    mx = fmaxf(mx, __shfl_xor(mx, 4));
                    mx = fmaxf(mx, __shfl_xor(mx, 8));
                    const float mo  = m_[h][r];
                    const float mn2 = fmaxf(mo, mx);
                    const float al  = exp2f((mo - mn2) * LOG2E);
                    const float p0  = exp2f((t0 - mn2) * LOG2E);
                    const float p1  = exp2f((t1 - mn2) * LOG2E);
                    float rs = p0 + p1;
                    rs += __shfl_xor(rs, 1);
                    rs += __shfl_xor(rs, 2);
                    rs += __shfl_xor(rs, 4);
                    rs += __shfl_xor(rs, 8);
                    m_[h][r]   = mn2;
                    l_[h][r]   = l_[h][r] * al + rs;
                    alpha[h][r]= al;
                    P[h][0][r] = p0; P[h][1][r] = p1;
                }
                // rescale O
                #pragma unroll
                for (int d = 0; d < 8; ++d) {
                    O[h][d][0] *= alpha[h][0]; O[h][d][1] *= alpha[h][1];
                    O[h][d][2] *= alpha[h][2]; O[h][d][3] *= alpha[h][3];
                }
                // P: C-layout -> LDS (per-wave private region)
                #pragma unroll
                for (int nt = 0; nt < 2; ++nt)
                    #pragma unroll
                    for (int r = 0; r < 4; ++r)
                        Plds[w][h][quad*4 + r][nt*16 + n] = f2bf(P[h][nt][r]);
            }
            // P A-frags (same-wave LDS ops are ordered; no barrier needed)
            bf16x8 Pf0 = *(bf16x8*)&Plds[w][0][n][quad*8];
            bf16x8 Pf1 = *(bf16x8*)&Plds[w][1][n][quad*8];
            // PV accumulate over 8 dv-tiles; V frags shared by both heads
            #pragma unroll
            for (int d = 0; d < 8; ++d) {
                ushort4 lo = *(ushort4*)&Vt[d*16 + n][quad*8];
                ushort4 hi = *(ushort4*)&Vt[d*16 + n][quad*8 + 4];
                bf16x8 vf;
                vf[0]=(short)lo.x; vf[1]=(short)lo.y; vf[2]=(short)lo.z; vf[3]=(short)lo.w;
                vf[4]=(short)hi.x; vf[5]=(short)hi.y; vf[6]=(short)hi.z; vf[7]=(short)hi.w;
                O[0][d] = __builtin_amdgcn_mfma_f32_16x16x32_bf16(Pf0, vf, O[0][d], 0, 0, 0);
                O[1][d] = __builtin_amdgcn_mfma_f32_16x16x32_bf16(Pf1, vf, O[1][d], 0, 0, 0);
            }
        }
    }

    // ---- epilogue: combine heads, RMS norm over 128, scale, store ----
    float* ob = out + (((size_t)(b*16 + hp)) * TSEQ + qw0) * DVDIM;
    #pragma unroll
    for (int r = 0; r < 4; ++r) {
        const float i1 = 1.0f   / l_[0][r];
        const float i2 = lambda / l_[1][r];
        float yv[8]; float ss = 0.f;
        #pragma unroll
        for (int d = 0; d < 8; ++d) {
            float yy = O[0][d][r] * i1 - O[1][d][r] * i2;
            yv[d] = yy; ss += yy * yy;
        }
        ss += __shfl_xor(ss, 1);
        ss += __shfl_xor(ss, 2);
        ss += __shfl_xor(ss, 4);
        ss += __shfl_xor(ss, 8);
        const float sc = rsqrtf(ss * (1.0f/128.0f) + RMS_EPS) * ONE_MINUS_LI;
        const int row = quad*4 + r;
        #pragma unroll
        for (int d = 0; d < 8; ++d) {
            const int dv = d*16 + n;
            ob[(size_t)row * DVDIM + dv] = yv[d] * sc * rmsw[dv];
        }
    }
}

extern "C" void kernel_launch(void* const* d_in, const int* in_sizes, int n_in,
                              void* d_out, int out_size, void* d_ws, size_t ws_size,
                              hipStream_t stream) {
    const float* q    = (const float*)d_in[0];
    const float* k    = (const float*)d_in[1];
    const float* v    = (const float*)d_in[2];
    // d_in[3] = mask (causal tril, hardcoded), d_in[9] = flash_attn flag (unused)
    const float* lq1  = (const float*)d_in[4];
    const float* lk1  = (const float*)d_in[5];
    const float* lq2  = (const float*)d_in[6];
    const float* lk2  = (const float*)d_in[7];
    const float* rmsw = (const float*)d_in[8];
    float* out = (float*)d_out;

    dim3 grid(TSEQ/64, 16, 4);   // (q-tile, head-pair, batch)
    dim3 block(256);
    diff_attn_kernel<<<grid, block, 0, stream>>>(q, k, v, lq1, lk1, lq2, lk2, rmsw, out);
}

// Round 2
// 302.547 us; speedup vs baseline: 1.5749x; 1.5749x over previous
//
#include <hip/hip_runtime.h>

// Differential attention, fused flash-style, f16 MFMA, S^T orientation (gfx950).
// B=4, T=1024, 16 head-pairs (32 QK heads), D_HEAD=64, V dim=128, causal.
//
// Key structure (R1):
//  - S^T = K·Q^T via operand swap: softmax reduction dim lands on C-rows
//    (quads) -> 2 shuffles per tile per head, per-lane scalar m/l/alpha.
//  - P^T in MFMA C-layout IS the B-operand layout of 16x16x16 f16 MFMA:
//    PV consumes P directly from registers (no LDS round-trip).
//  - Register prefetch: tile t+1 global loads issued after the "LDS ready"
//    barrier, consumed in t+1's write phase (latency hidden under compute).

typedef _Float16 f16x4 __attribute__((ext_vector_type(4)));
typedef _Float16 f16x8 __attribute__((ext_vector_type(8)));
typedef float    f32x4 __attribute__((ext_vector_type(4)));

constexpr int   TSEQ        = 1024;
constexpr int   DQK         = 64;
constexpr int   DVDIM       = 128;
constexpr float SCALING     = 0.125f;                 // 1/sqrt(64)
constexpr float LAMBDA_INIT = 0.7836057665316245f;    // 0.8 - 0.6*exp(-3.6)
constexpr float ONE_MINUS_LI= 1.0f - LAMBDA_INIT;
constexpr float RMS_EPS     = 1e-6f;
constexpr float LOG2E       = 1.4426950408889634f;

__global__ __launch_bounds__(256, 3)
void diff_attn_kernel(const float* __restrict__ qg, const float* __restrict__ kg,
                      const float* __restrict__ vg,
                      const float* __restrict__ lq1, const float* __restrict__ lk1,
                      const float* __restrict__ lq2, const float* __restrict__ lk2,
                      const float* __restrict__ rmsw, float* __restrict__ out)
{
    // K tiles (2 heads x 32 s x 64 d), rows padded 64->72 halves (144B, 16B-aligned)
    __shared__ _Float16 Klds[2][32][72];
    // V tile transposed [dv][s], rows padded 32->36 halves (72B, 8B-aligned)
    __shared__ _Float16 Vt[128][36];

    const int qt   = gridDim.x - 1 - blockIdx.x;  // heavy q-tiles first
    const int hp   = blockIdx.y;
    const int b    = blockIdx.z;
    const int t    = threadIdx.x;
    const int w    = t >> 6;
    const int lane = t & 63;
    const int n    = lane & 15;   // col index of C (q); m of A-frags
    const int quad = lane >> 4;   // k-chunk / C-row-group index
    const int qbase = qt * 64;
    const int qw0   = qbase + w * 16;   // this wave's first q row
    const int qrow  = qw0 + n;          // this lane's q row

    // ---- lambda_final: wave-parallel dot + butterfly reduce ----
    float a1 = lq1[hp*64 + lane] * lk1[hp*64 + lane];
    float a2 = lq2[hp*64 + lane] * lk2[hp*64 + lane];
    #pragma unroll
    for (int d = 1; d < 64; d <<= 1) { a1 += __shfl_xor(a1, d); a2 += __shfl_xor(a2, d); }
    const float lambda = __expf(a1) - __expf(a2) + LAMBDA_INIT;

    // ---- Q fragments (B-operand of S^T MFMA), pre-scaled into exp2 domain ----
    const float qscale = SCALING * LOG2E;
    f16x8 Qf[2][2];
    #pragma unroll
    for (int h = 0; h < 2; ++h) {
        const float* qp = qg + (((size_t)(b*32 + hp*2 + h)) * TSEQ + qrow) * DQK + quad*8;
        #pragma unroll
        for (int ks = 0; ks < 2; ++ks) {
            float4 x = *(const float4*)(qp + ks*32);
            float4 y = *(const float4*)(qp + ks*32 + 4);
            f16x8 f;
            f[0]=(_Float16)(x.x*qscale); f[1]=(_Float16)(x.y*qscale);
            f[2]=(_Float16)(x.z*qscale); f[3]=(_Float16)(x.w*qscale);
            f[4]=(_Float16)(y.x*qscale); f[5]=(_Float16)(y.y*qscale);
            f[6]=(_Float16)(y.z*qscale); f[7]=(_Float16)(y.w*qscale);
            Qf[h][ks] = f;
        }
    }

    // ---- O^T accumulators (row = dv_local, col = q) + per-lane m/l ----
    f32x4 O[2][8];
    #pragma unroll
    for (int h = 0; h < 2; ++h)
        #pragma unroll
        for (int d = 0; d < 8; ++d) O[h][d] = (f32x4){0.f,0.f,0.f,0.f};
    float m_[2] = { -__builtin_huge_valf(), -__builtin_huge_valf() };
    float l_[2] = { 0.f, 0.f };

    const float* kb = kg + ((size_t)(b*32 + hp*2)) * TSEQ * DQK;
    const float* vb = vg + ((size_t)(b*16 + hp))   * TSEQ * DVDIM;

    // prefetch register buffers
    const int dvb = (t & 15) * 8;       // V staging: 8 consecutive dv
    const int s0  = (t >> 4) * 2;       // V staging: 2 consecutive s
    float4 kr[2][2], vr[4];

    auto load_tile = [&](int sbase) {
        #pragma unroll
        for (int i = 0; i < 2; ++i) {
            const int c  = i*256 + t;
            const int h  = c >> 8, sr = (c >> 3) & 31, d8 = c & 7;
            const float* p = kb + ((size_t)h*TSEQ + sbase + sr)*DQK + d8*8;
            kr[i][0] = *(const float4*)p;
            kr[i][1] = *(const float4*)(p + 4);
        }
        const float* vp = vb + (size_t)(sbase + s0)*DVDIM + dvb;
        vr[0] = *(const float4*)vp;
        vr[1] = *(const float4*)(vp + 4);
        vr[2] = *(const float4*)(vp + DVDIM);
        vr[3] = *(const float4*)(vp + DVDIM + 4);
    };

    auto write_tile = [&]() {
        #pragma unroll
        for (int i = 0; i < 2; ++i) {
            const int c  = i*256 + t;
            const int h  = c >> 8, sr = (c >> 3) & 31, d8 = c & 7;
            f16x8 kk;
            kk[0]=(_Float16)kr[i][0].x; kk[1]=(_Float16)kr[i][0].y;
            kk[2]=(_Float16)kr[i][0].z; kk[3]=(_Float16)kr[i][0].w;
            kk[4]=(_Float16)kr[i][1].x; kk[5]=(_Float16)kr[i][1].y;
            kk[6]=(_Float16)kr[i][1].z; kk[7]=(_Float16)kr[i][1].w;
            *(f16x8*)&Klds[h][sr][d8*8] = kk;
        }
        float v0[8] = {vr[0].x,vr[0].y,vr[0].z,vr[0].w, vr[1].x,vr[1].y,vr[1].z,vr[1].w};
        float v1[8] = {vr[2].x,vr[2].y,vr[2].z,vr[2].w, vr[3].x,vr[3].y,vr[3].z,vr[3].w};
        #pragma unroll
        for (int mI = 0; mI < 8; ++mI) {
            _Float16 lo = (_Float16)v0[mI], hi = (_Float16)v1[mI];
            _Float16* dst = &Vt[dvb + mI][s0];
            dst[0] = lo; dst[1] = hi;   // 4B-aligned pair store
        }
    };

    const int nT = (qbase + 64) >> 5;   // s-tiles of 32, causal upper bound
    load_tile(0);

    for (int tile = 0; tile < nT; ++tile) {
        const int sbase = tile << 5;
        __syncthreads();                 // previous tile's readers done
        write_tile();
        __syncthreads();                 // LDS ready
        if (tile + 1 < nT) load_tile((tile + 1) << 5);   // prefetch under compute

        if (sbase <= qw0 + 15) {         // wave-uniform causal early-out
            f16x4 pb[2][2];
            #pragma unroll
            for (int h = 0; h < 2; ++h) {
                // S^T = K·Q^T (already in exp2 domain), two 16-row s-subtiles
                f32x4 St[2];
                #pragma unroll
                for (int sub = 0; sub < 2; ++sub) {
                    f16x8 k0 = *(const f16x8*)&Klds[h][sub*16 + n][quad*8];
                    f16x8 k1 = *(const f16x8*)&Klds[h][sub*16 + n][32 + quad*8];
                    f32x4 c = (f32x4){0.f,0.f,0.f,0.f};
                    c = __builtin_amdgcn_mfma_f32_16x16x32_f16(k0, Qf[h][0], c, 0, 0, 0);
                    c = __builtin_amdgcn_mfma_f32_16x16x32_f16(k1, Qf[h][1], c, 0, 0, 0);
                    St[sub] = c;
                }
                // causal mask; rows = s, col (this lane) = qrow
                float vals[8];
                #pragma unroll
                for (int sub = 0; sub < 2; ++sub)
                    #pragma unroll
                    for (int r = 0; r < 4; ++r) {
                        const int s = sbase + sub*16 + quad*4 + r;
                        vals[sub*4 + r] = (s <= qrow) ? St[sub][r] : -__builtin_huge_valf();
                    }
                // online softmax: in-lane 8 + 2 cross-quad shuffles
                float mx = vals[0];
                #pragma unroll
                for (int j = 1; j < 8; ++j) mx = fmaxf(mx, vals[j]);
                mx = fmaxf(mx, __shfl_xor(mx, 16));
                mx = fmaxf(mx, __shfl_xor(mx, 32));
                const float mold = m_[h];
                const float mnew = fmaxf(mold, mx);
                const float alpha = exp2f(mold - mnew);
                float p[8], rs = 0.f;
                #pragma unroll
                for (int j = 0; j < 8; ++j) { p[j] = exp2f(vals[j] - mnew); rs += p[j]; }
                rs += __shfl_xor(rs, 16);
                rs += __shfl_xor(rs, 32);
                m_[h] = mnew;
                l_[h] = l_[h] * alpha + rs;
                #pragma unroll
                for (int d = 0; d < 8; ++d) {
                    O[h][d][0] *= alpha; O[h][d][1] *= alpha;
                    O[h][d][2] *= alpha; O[h][d][3] *= alpha;
                }
                // P^T already in B-operand layout (k = quad*4 + j)
                pb[h][0] = (f16x4){(_Float16)p[0],(_Float16)p[1],(_Float16)p[2],(_Float16)p[3]};
                pb[h][1] = (f16x4){(_Float16)p[4],(_Float16)p[5],(_Float16)p[6],(_Float16)p[7]};
            }
            // PV: O^T += V^T · P^T ; V frags shared by both heads
            #pragma unroll
            for (int d = 0; d < 8; ++d) {
                #pragma unroll
                for (int sub = 0; sub < 2; ++sub) {
                    f16x4 va = *(const f16x4*)&Vt[d*16 + n][sub*16 + quad*4];
                    O[0][d] = __builtin_amdgcn_mfma_f32_16x16x16f16(va, pb[0][sub], O[0][d], 0, 0, 0);
                    O[1][d] = __builtin_amdgcn_mfma_f32_16x16x16f16(va, pb[1][sub], O[1][d], 0, 0, 0);
                }
            }
        }
    }

    // ---- epilogue: combine heads, RMS over dv=128 (in-lane 32 + 2 shuffles) ----
    const float i1 = 1.0f   / l_[0];
    const float i2 = lambda / l_[1];
    float yv[8][4];
    float ss = 0.f;
    #pragma unroll
    for (int d = 0; d < 8; ++d)
        #pragma unroll
        for (int r = 0; r < 4; ++r) {
            const float y = O[0][d][r] * i1 - O[1][d][r] * i2;
            yv[d][r] = y; ss += y * y;
        }
    ss += __shfl_xor(ss, 16);
    ss += __shfl_xor(ss, 32);
    const float sc = rsqrtf(ss * (1.0f/128.0f) + RMS_EPS) * ONE_MINUS_LI;

    float* ob = out + (((size_t)(b*16 + hp)) * TSEQ + qrow) * DVDIM;
    #pragma unroll
    for (int d = 0; d < 8; ++d) {
        const int dv = d*16 + quad*4;
        float4 wv = *(const float4*)&rmsw[dv];
        float4 o;
        o.x = yv[d][0] * sc * wv.x;
        o.y = yv[d][1] * sc * wv.y;
        o.z = yv[d][2] * sc * wv.z;
        o.w = yv[d][3] * sc * wv.w;
        *(float4*)(ob + dv) = o;
    }
}

extern "C" void kernel_launch(void* const* d_in, const int* in_sizes, int n_in,
                              void* d_out, int out_size, void* d_ws, size_t ws_size,
                              hipStream_t stream) {
    const float* q    = (const float*)d_in[0];
    const float* k    = (const float*)d_in[1];
    const float* v    = (const float*)d_in[2];
    // d_in[3] = mask (causal tril, hardcoded), d_in[9] = flash_attn flag (unused)
    const float* lq1  = (const float*)d_in[4];
    const float* lk1  = (const float*)d_in[5];
    const float* lq2  = (const float*)d_in[6];
    const float* lk2  = (const float*)d_in[7];
    const float* rmsw = (const float*)d_in[8];
    float* out = (float*)d_out;

    dim3 grid(TSEQ/64, 16, 4);   // (q-tile, head-pair, batch)
    dim3 block(256);
    diff_attn_kernel<<<grid, block, 0, stream>>>(q, k, v, lq1, lk1, lq2, lk2, rmsw, out);
}

// Round 3
// 224.510 us; speedup vs baseline: 2.1224x; 1.3476x over previous
//
#include <hip/hip_runtime.h>

// Differential attention, fused flash-style, f16 MFMA, S^T orientation (gfx950).
// B=4, T=1024, 16 head-pairs (32 QK heads), D_HEAD=64, V dim=128, causal.
//
// R2: perfectly balanced grid via q-tile pairing (block a does q-tiles a and
// 15-a -> every block runs exactly 17 64-s iterations incl. 2 diagonal tiles);
// 64-s K/V tiles (half the barriers per unit work, 2x ILP per phase);
// V^T LDS column-rotation swizzle (write conflicts 8-way -> 2-way/free).

typedef _Float16 f16x4 __attribute__((ext_vector_type(4)));
typedef _Float16 f16x8 __attribute__((ext_vector_type(8)));
typedef float    f32x4 __attribute__((ext_vector_type(4)));

constexpr int   TSEQ        = 1024;
constexpr int   DQK         = 64;
constexpr int   DVDIM       = 128;
constexpr float SCALING     = 0.125f;                 // 1/sqrt(64)
constexpr float LAMBDA_INIT = 0.7836057665316245f;    // 0.8 - 0.6*exp(-3.6)
constexpr float ONE_MINUS_LI= 1.0f - LAMBDA_INIT;
constexpr float RMS_EPS     = 1e-6f;
constexpr float LOG2E       = 1.4426950408889634f;

__global__ __launch_bounds__(256, 2)
void diff_attn_kernel(const float* __restrict__ qg, const float* __restrict__ kg,
                      const float* __restrict__ vg,
                      const float* __restrict__ lq1, const float* __restrict__ lk1,
                      const float* __restrict__ lq2, const float* __restrict__ lk2,
                      const float* __restrict__ rmsw, float* __restrict__ out)
{
    // K tiles (2 heads x 64 s x 64 d), rows padded 64->72 halves (144B)
    __shared__ _Float16 Klds[2][64][72];
    // V^T tile [dv][s], rows padded 64->68 halves, column-rotation swizzled
    __shared__ _Float16 Vt[128][68];

    const int a    = blockIdx.x;   // pair index 0..7 -> q-tiles {a, 15-a}
    const int hp   = blockIdx.y;
    const int b    = blockIdx.z;
    const int t    = threadIdx.x;
    const int w    = t >> 6;
    const int lane = t & 63;
    const int n    = lane & 15;    // col index of C (q); m of A-frags
    const int quad = lane >> 4;

    // ---- lambda_final: wave-parallel dot + butterfly reduce ----
    float a1 = lq1[hp*64 + lane] * lk1[hp*64 + lane];
    float a2 = lq2[hp*64 + lane] * lk2[hp*64 + lane];
    #pragma unroll
    for (int d = 1; d < 64; d <<= 1) { a1 += __shfl_xor(a1, d); a2 += __shfl_xor(a2, d); }
    const float lambda = __expf(a1) - __expf(a2) + LAMBDA_INIT;

    const float* kb = kg + ((size_t)(b*32 + hp*2)) * TSEQ * DQK;
    const float* vb = vg + ((size_t)(b*16 + hp))   * TSEQ * DVDIM;

    // ---- staging geometry ----
    const int jj   = t & 15;            // V: dv-block owner
    const int sg   = t >> 4;            // V: s-group
    const int dvb  = jj * 8;
    const int s0   = sg * 4;
    const int rotw = (jj & 7) * 8;      // V write swizzle rotation (halves)
    const int d8   = t & 7;             // K: d-chunk

    float4 kr[4][2], vr[8];

    auto load_tile = [&](int sbase) {
        #pragma unroll
        for (int i = 0; i < 4; ++i) {
            const int row = (i*256 + t) >> 3;        // 0..127 (h*64 + s)
            const int h = row >> 6, sr = row & 63;
            const float* p = kb + ((size_t)h*TSEQ + sbase + sr)*DQK + d8*8;
            kr[i][0] = *(const float4*)p;
            kr[i][1] = *(const float4*)(p + 4);
        }
        const float* vp = vb + (size_t)(sbase + s0)*DVDIM + dvb;
        #pragma unroll
        for (int r = 0; r < 4; ++r) {
            vr[2*r]   = *(const float4*)(vp + r*DVDIM);
            vr[2*r+1] = *(const float4*)(vp + r*DVDIM + 4);
        }
    };

    auto write_tile = [&]() {
        #pragma unroll
        for (int i = 0; i < 4; ++i) {
            const int row = (i*256 + t) >> 3;
            const int h = row >> 6, sr = row & 63;
            f16x8 kk;
            kk[0]=(_Float16)kr[i][0].x; kk[1]=(_Float16)kr[i][0].y;
            kk[2]=(_Float16)kr[i][0].z; kk[3]=(_Float16)kr[i][0].w;
            kk[4]=(_Float16)kr[i][1].x; kk[5]=(_Float16)kr[i][1].y;
            kk[6]=(_Float16)kr[i][1].z; kk[7]=(_Float16)kr[i][1].w;
            *(f16x8*)&Klds[h][sr][d8*8] = kk;
        }
        float vrow[4][8];
        #pragma unroll
        for (int r = 0; r < 4; ++r) {
            vrow[r][0]=vr[2*r].x;   vrow[r][1]=vr[2*r].y;
            vrow[r][2]=vr[2*r].z;   vrow[r][3]=vr[2*r].w;
            vrow[r][4]=vr[2*r+1].x; vrow[r][5]=vr[2*r+1].y;
            vrow[r][6]=vr[2*r+1].z; vrow[r][7]=vr[2*r+1].w;
        }
        #pragma unroll
        for (int mI = 0; mI < 8; ++mI) {
            f16x4 pk;
            pk[0]=(_Float16)vrow[0][mI]; pk[1]=(_Float16)vrow[1][mI];
            pk[2]=(_Float16)vrow[2][mI]; pk[3]=(_Float16)vrow[3][mI];
            *(f16x4*)&Vt[dvb + mI][(s0 + rotw) & 63] = pk;
        }
    };

    const float qscale = SCALING * LOG2E;
    load_tile(0);

    for (int part = 0; part < 2; ++part) {
        const int qt    = part ? (15 - a) : a;
        const int qbase = qt * 64;
        const int qw0   = qbase + w * 16;
        const int qrow  = qw0 + n;
        const int nT    = qt + 1;

        // Q fragments (B-operand of S^T MFMA), pre-scaled into exp2 domain
        f16x8 Qf[2][2];
        #pragma unroll
        for (int h = 0; h < 2; ++h) {
            const float* qp = qg + (((size_t)(b*32 + hp*2 + h)) * TSEQ + qrow) * DQK + quad*8;
            #pragma unroll
            for (int ks = 0; ks < 2; ++ks) {
                float4 x = *(const float4*)(qp + ks*32);
                float4 y = *(const float4*)(qp + ks*32 + 4);
                f16x8 f;
                f[0]=(_Float16)(x.x*qscale); f[1]=(_Float16)(x.y*qscale);
                f[2]=(_Float16)(x.z*qscale); f[3]=(_Float16)(x.w*qscale);
                f[4]=(_Float16)(y.x*qscale); f[5]=(_Float16)(y.y*qscale);
                f[6]=(_Float16)(y.z*qscale); f[7]=(_Float16)(y.w*qscale);
                Qf[h][ks] = f;
            }
        }

        f32x4 O[2][8];
        #pragma unroll
        for (int h = 0; h < 2; ++h)
            #pragma unroll
            for (int d = 0; d < 8; ++d) O[h][d] = (f32x4){0.f,0.f,0.f,0.f};
        float m_[2] = { -__builtin_huge_valf(), -__builtin_huge_valf() };
        float l_[2] = { 0.f, 0.f };

        for (int tile = 0; tile < nT; ++tile) {
            const int sbase = tile * 64;
            __syncthreads();                // previous readers done
            write_tile();
            __syncthreads();                // LDS ready
            if (tile + 1 < nT)      load_tile((tile + 1) * 64);  // prefetch
            else if (part == 0)     load_tile(0);                // part 1 tile 0

            const bool diag = (tile == qt);
            const int  nact = diag ? (w + 1) : 4;   // active 16-s sub-tiles

            f16x4 pb[2][4];
            #pragma unroll
            for (int h = 0; h < 2; ++h) {
                f32x4 St[4];
                #pragma unroll
                for (int sub = 0; sub < 4; ++sub) {
                    if (sub < nact) {
                        f16x8 k0 = *(const f16x8*)&Klds[h][sub*16 + n][quad*8];
                        f16x8 k1 = *(const f16x8*)&Klds[h][sub*16 + n][32 + quad*8];
                        f32x4 c = (f32x4){0.f,0.f,0.f,0.f};
                        c = __builtin_amdgcn_mfma_f32_16x16x32_f16(k0, Qf[h][0], c, 0, 0, 0);
                        c = __builtin_amdgcn_mfma_f32_16x16x32_f16(k1, Qf[h][1], c, 0, 0, 0);
                        St[sub] = c;
                    }
                }
                float vals[16];
                #pragma unroll
                for (int sub = 0; sub < 4; ++sub) {
                    if (sub < nact) {
                        #pragma unroll
                        for (int r = 0; r < 4; ++r) {
                            const int s = sbase + sub*16 + quad*4 + r;
                            float x = St[sub][r];
                            if (diag && s > qrow) x = -__builtin_huge_valf();
                            vals[sub*4 + r] = x;
                        }
                    }
                }
                float mx = -__builtin_huge_valf();
                #pragma unroll
                for (int sub = 0; sub < 4; ++sub)
                    if (sub < nact)
                        #pragma unroll
                        for (int r = 0; r < 4; ++r) mx = fmaxf(mx, vals[sub*4 + r]);
                mx = fmaxf(mx, __shfl_xor(mx, 16));
                mx = fmaxf(mx, __shfl_xor(mx, 32));
                const float mold  = m_[h];
                const float mnew  = fmaxf(mold, mx);
                const float alpha = exp2f(mold - mnew);
                float rs = 0.f;
                #pragma unroll
                for (int sub = 0; sub < 4; ++sub) {
                    if (sub < nact) {
                        #pragma unroll
                        for (int r = 0; r < 4; ++r) {
                            const float p = exp2f(vals[sub*4 + r] - mnew);
                            rs += p;
                            pb[h][sub][r] = (_Float16)p;
                        }
                    }
                }
                rs += __shfl_xor(rs, 16);
                rs += __shfl_xor(rs, 32);
                m_[h] = mnew;
                l_[h] = l_[h] * alpha + rs;
                #pragma unroll
                for (int d = 0; d < 8; ++d) {
                    O[h][d][0] *= alpha; O[h][d][1] *= alpha;
                    O[h][d][2] *= alpha; O[h][d][3] *= alpha;
                }
            }
            // PV: O^T += V^T · P^T ; V frags shared by both heads
            #pragma unroll
            for (int dd = 0; dd < 8; ++dd) {
                const int rot_r = ((2*dd + (n >> 3)) & 7) * 8;
                #pragma unroll
                for (int sub = 0; sub < 4; ++sub) {
                    if (sub < nact) {
                        f16x4 va = *(const f16x4*)&Vt[dd*16 + n][(sub*16 + quad*4 + rot_r) & 63];
                        O[0][dd] = __builtin_amdgcn_mfma_f32_16x16x16f16(va, pb[0][sub], O[0][dd], 0, 0, 0);
                        O[1][dd] = __builtin_amdgcn_mfma_f32_16x16x16f16(va, pb[1][sub], O[1][dd], 0, 0, 0);
                    }
                }
            }
        }

        // ---- epilogue: combine heads, RMS over dv=128, scale, store ----
        const float i1 = 1.0f   / l_[0];
        const float i2 = lambda / l_[1];
        float yv[8][4];
        float ss = 0.f;
        #pragma unroll
        for (int d = 0; d < 8; ++d)
            #pragma unroll
            for (int r = 0; r < 4; ++r) {
                const float y = O[0][d][r] * i1 - O[1][d][r] * i2;
                yv[d][r] = y; ss += y * y;
            }
        ss += __shfl_xor(ss, 16);
        ss += __shfl_xor(ss, 32);
        const float sc = rsqrtf(ss * (1.0f/128.0f) + RMS_EPS) * ONE_MINUS_LI;

        float* ob = out + (((size_t)(b*16 + hp)) * TSEQ + qrow) * DVDIM;
        #pragma unroll
        for (int d = 0; d < 8; ++d) {
            const int dv = d*16 + quad*4;
            float4 wv = *(const float4*)&rmsw[dv];
            float4 o;
            o.x = yv[d][0] * sc * wv.x;
            o.y = yv[d][1] * sc * wv.y;
            o.z = yv[d][2] * sc * wv.z;
            o.w = yv[d][3] * sc * wv.w;
            *(float4*)(ob + dv) = o;
        }
    }
}

extern "C" void kernel_launch(void* const* d_in, const int* in_sizes, int n_in,
                              void* d_out, int out_size, void* d_ws, size_t ws_size,
                              hipStream_t stream) {
    const float* q    = (const float*)d_in[0];
    const float* k    = (const float*)d_in[1];
    const float* v    = (const float*)d_in[2];
    // d_in[3] = mask (causal tril, hardcoded), d_in[9] = flash_attn flag (unused)
    const float* lq1  = (const float*)d_in[4];
    const float* lk1  = (const float*)d_in[5];
    const float* lq2  = (const float*)d_in[6];
    const float* lk2  = (const float*)d_in[7];
    const float* rmsw = (const float*)d_in[8];
    float* out = (float*)d_out;

    dim3 grid(8, 16, 4);   // (q-tile pair, head-pair, batch)
    dim3 block(256);
    diff_attn_kernel<<<grid, block, 0, stream>>>(q, k, v, lq1, lk1, lq2, lk2, rmsw, out);
}